// Round 11
// baseline (189.356 us; speedup 1.0000x reference)
//
#include <hip/hip_runtime.h>
#include <math.h>

#define NATOMS 5
#define NEXP 18
#define NBEAD 4
#define EPSV 1e-8f
#define ML2 (0.02f * 0.02f)

typedef float vf4a __attribute__((ext_vector_type(4), aligned(16)));

__device__ __forceinline__ unsigned char decode_combo(float beadf, float gatef) {
    beadf = isfinite(beadf) ? beadf : 0.f;
    gatef = isfinite(gatef) ? gatef : 0.f;
    gatef = fminf(fmaxf(gatef, -1e6f), 1e6f);
    beadf = fminf(fmaxf(beadf, -1e6f), 1e6f);
    int rid = min(max((int)rintf(gatef) - 1, 0), NEXP - 1);
    int bid = min(max((int)rintf(beadf), 0), NBEAD - 1);
    return (unsigned char)(rid * NBEAD + bid);
}

// Pre-resolve gate/bead -> combo byte per row, and pack triplet tables.
// Two consecutive rows of x = 76 floats = 19 aligned float4 chunks; cols 36/37
// of row0 are chunk9.xy, of row1 chunk18.zw -> aligned 16B loads, no splits.
__global__ __launch_bounds__(256) void gate_kernel(
    const float* __restrict__ xin, const int* __restrict__ trip,
    const int* __restrict__ valid, int4* __restrict__ ptbl,
    unsigned char* __restrict__ combo, int n) {
    const int tid = blockIdx.x * 256 + threadIdx.x;

    // ---- pack triplet tables (block 0 only) ----
    if (blockIdx.x == 0 && threadIdx.x < NEXP * NBEAD) {
        int c = threadIdx.x;
        unsigned w[4] = {0u, 0u, 0u, 0u};
#pragma unroll
        for (int t = 0; t < 8; t++) {
            int b = c * 8 + t;
            int i = trip[b * 3 + 0], j = trip[b * 3 + 1], k = trip[b * 3 + 2];
            unsigned ok = (i >= 0 && j >= 0 && k >= 0 && valid[b] > 0) ? 1u : 0u;
            unsigned oi = 3u * (unsigned)min(max(i, 0), NATOMS - 1);
            unsigned oj = 3u * (unsigned)min(max(j, 0), NATOMS - 1);
            unsigned ov = 3u * (unsigned)min(max(k, 0), NATOMS - 1);
            unsigned e = oi | (oj << 4) | (ov << 8) | (ok << 12);
            w[t >> 1] |= e << ((t & 1) * 16);
        }
        ptbl[c] = make_int4((int)w[0], (int)w[1], (int)w[2], (int)w[3]);
    }

    // ---- per-pair gate decode ----
    const int row0 = tid * 2;
    if (row0 < n) {
        const vf4a* base = (const vf4a*)(xin + (size_t)tid * 76);
        vf4a c9 = __builtin_nontemporal_load(base + 9);    // floats 36..39
        combo[row0] = decode_combo(c9.x, c9.y);            // row0: c36=bead, c37=gate
        if (row0 + 1 < n) {
            vf4a c18 = __builtin_nontemporal_load(base + 18);  // floats 72..75
            combo[row0 + 1] = decode_combo(c18.z, c18.w);      // row1: c74, c75
        }
    }
}

// One wave per block, 64 rows per wave. Coalesced NT (L1-bypass) staging into
// LDS (16 lines/instr, zero splits). No xin access - combo byte per row is a
// single coalesced line per wave. LDS: 3*960*4 = 11520 B -> 13 wave-blocks/CU.
__global__ __launch_bounds__(64) void loss_kernel(
    const unsigned char* __restrict__ combo, const float* __restrict__ y_true,
    const float* __restrict__ y_pred, const float* __restrict__ mask,
    const int4* __restrict__ ptbl, float* __restrict__ partial, int n) {
    __shared__ float sT[960];  // 64 rows x 15
    __shared__ float sP[960];
    __shared__ float sM[960];

    const int tid = threadIdx.x;  // 0..63
    const int rbase = blockIdx.x * 64;
    const int row = rbase + tid;
    const size_t dbase = (size_t)rbase * 15;  // dword offset, 3840B-aligned
    const long long total = (long long)n * 15;

    // ---- combo byte: one 64B line per wave ----
    unsigned char cb = 0;
    if (row < n) cb = combo[row];

    // ---- coalesced NT bulk loads: chunk q = k*64+tid, lane-consecutive ----
    const vf4a* qT = (const vf4a*)(y_true + dbase);
    const vf4a* qP = (const vf4a*)(y_pred + dbase);
    const vf4a* qM = (const vf4a*)(mask + dbase);
    vf4a tC[4], pC[4], mC[4];
    bool ok[4];
#pragma unroll
    for (int k = 0; k < 4; k++) {
        int q = k * 64 + tid;
        ok[k] = (q < 240) && (dbase + 4 * (long long)q + 4 <= total);
        if (ok[k]) {
            tC[k] = __builtin_nontemporal_load(qT + q);
            pC[k] = __builtin_nontemporal_load(qP + q);
            mC[k] = __builtin_nontemporal_load(qM + q);
        }
    }
#pragma unroll
    for (int k = 0; k < 4; k++) {
        int q = k * 64 + tid;
        if (ok[k]) {
            ((vf4a*)sT)[q] = tC[k];
            ((vf4a*)sP)[q] = pC[k];
            ((vf4a*)sM)[q] = mC[k];
        }
    }
    __syncthreads();  // 1-wave block: trivially satisfied

    float result = 0.f;
    if (row < n) {
        const float* st = sT + tid * 15;  // stride 15 -> 2-way bank alias = free
        const float* sp = sP + tid * 15;
        const float* sm = sM + tid * 15;

        // ---- mask bits (binary mask -> exact) ----
        unsigned mrow = 0u;
#pragma unroll
        for (int c = 0; c < 15; c++) mrow |= (sm[c] > 0.f ? 1u : 0u) << c;

        // ---- atom MSE ----
        float num_a = 0.f, den_a = 0.f;
        unsigned avm2 = 0u;  // validity bit at premultiplied offset 3*a
#pragma unroll
        for (int a = 0; a < 5; a++) {
            unsigned mb = (mrow >> (3 * a)) & 7u;
            float d0 = st[3 * a + 0] - sp[3 * a + 0];
            float d1 = st[3 * a + 1] - sp[3 * a + 1];
            float d2 = st[3 * a + 2] - sp[3 * a + 2];
            float se = (mb & 1u ? d0 * d0 : 0.f) + (mb & 2u ? d1 * d1 : 0.f) +
                       (mb & 4u ? d2 * d2 : 0.f);
            if (mb) { num_a += se; den_a += 1.f; avm2 |= 1u << (3 * a); }
        }
        result = num_a / (den_a + EPSV);

        // ---- table fetch (tiny, cached) ----
        int4 pk = ptbl[cb];
        unsigned tw0 = (unsigned)pk.x, tw1 = (unsigned)pk.y;
        unsigned tw2 = (unsigned)pk.z, tw3 = (unsigned)pk.w;

        // ---- angle part: dynamic gathers from own LDS row ----
        float num_g = 0.f, den_g = 0.f;
#pragma unroll
        for (int t = 0; t < 8; t++) {
            unsigned wrd = (t < 2) ? tw0 : (t < 4) ? tw1 : (t < 6) ? tw2 : tw3;
            unsigned e = (wrd >> ((t & 1) * 16)) & 0xffffu;
            int oi = e & 15, oj = (e >> 4) & 15, ov = (e >> 8) & 15;
            bool wok = ((e >> 12) & 1u) != 0u;

            float tix = st[oi], tiy = st[oi + 1], tiz = st[oi + 2];
            float tjx = st[oj], tjy = st[oj + 1], tjz = st[oj + 2];
            float tkx = st[ov], tky = st[ov + 1], tkz = st[ov + 2];
            float pix = sp[oi], piy = sp[oi + 1], piz = sp[oi + 2];
            float pjx = sp[oj], pjy = sp[oj + 1], pjz = sp[oj + 2];
            float pkx = sp[ov], pky = sp[ov + 1], pkz = sp[ov + 2];

            float v1tx = tix - tjx, v1ty = tiy - tjy, v1tz = tiz - tjz;
            float v2tx = tkx - tjx, v2ty = tky - tjy, v2tz = tkz - tjz;
            float v1px = pix - pjx, v1py = piy - pjy, v1pz = piz - pjz;
            float v2px = pkx - pjx, v2py = pky - pjy, v2pz = pkz - pjz;

            float l1t = fmaf(v1tx, v1tx, fmaf(v1ty, v1ty, v1tz * v1tz));
            float l2t = fmaf(v2tx, v2tx, fmaf(v2ty, v2ty, v2tz * v2tz));
            float l1p = fmaf(v1px, v1px, fmaf(v1py, v1py, v1pz * v1pz));
            float l2p = fmaf(v2px, v2px, fmaf(v2py, v2py, v2pz * v2pz));

            bool okv = wok && ((avm2 >> oi) & 1) && ((avm2 >> oj) & 1) &&
                       ((avm2 >> ov) & 1) && (l1t > ML2) && (l2t > ML2) &&
                       (l1p > ML2) && (l2p > ML2);

            float rt = __builtin_amdgcn_rsqf(fmaxf(l1t, ML2) * fmaxf(l2t, ML2));
            float rp = __builtin_amdgcn_rsqf(fmaxf(l1p, ML2) * fmaxf(l2p, ML2));

            float dott = fmaf(v1tx, v2tx, fmaf(v1ty, v2ty, v1tz * v2tz));
            float dotp = fmaf(v1px, v2px, fmaf(v1py, v2py, v1pz * v2pz));
            float cut = dott * rt;
            float cup = dotp * rp;
            float cost = fminf(fmaxf(cut, -1.f + 1e-6f), 1.f - 1e-6f);
            float cosp = fminf(fmaxf(cup, -1.f + 1e-6f), 1.f - 1e-6f);
            float sint = __builtin_amdgcn_sqrtf(fmaxf(fmaf(-cut, cut, 1.f), 0.f));
            float sinp = __builtin_amdgcn_sqrtf(fmaxf(fmaf(-cup, cup, 1.f), 0.f));

            float dc = cosp - cost, dsn = sinp - sint;
            if (okv) { num_g += fmaf(dc, dc, dsn * dsn); den_g += 1.f; }
        }
        result += num_g / (den_g + EPSV);
    }

    // ---- wave reduction: block == wave ----
#pragma unroll
    for (int off = 32; off > 0; off >>= 1)
        result += __shfl_down(result, off, 64);
    if (tid == 0) partial[blockIdx.x] = result;
}

__global__ __launch_bounds__(256) void reduce_kernel(const float* __restrict__ partial,
                                                     float* __restrict__ out, int m,
                                                     float inv_n) {
    __shared__ float red[4];
    float s = 0.f;
    for (int i = threadIdx.x; i < m; i += 256) s += partial[i];
#pragma unroll
    for (int off = 32; off > 0; off >>= 1) s += __shfl_down(s, off, 64);
    int lane = threadIdx.x & 63, wv = threadIdx.x >> 6;
    if (lane == 0) red[wv] = s;
    __syncthreads();
    if (threadIdx.x == 0) out[0] = (red[0] + red[1] + red[2] + red[3]) * inv_n;
}

extern "C" void kernel_launch(void* const* d_in, const int* in_sizes, int n_in,
                              void* d_out, int out_size, void* d_ws, size_t ws_size,
                              hipStream_t stream) {
    const float* x = (const float*)d_in[0];
    const float* y_true = (const float*)d_in[1];
    const float* y_pred = (const float*)d_in[2];
    const float* mask = (const float*)d_in[3];
    const int* trip = (const int*)d_in[4];
    const int* valid = (const int*)d_in[5];
    float* out = (float*)d_out;

    int4* ptbl = (int4*)d_ws;                                 // 72 * 16 B
    unsigned char* combo = (unsigned char*)d_ws + 4096;       // n bytes
    float* partial = (float*)((char*)d_ws + 4096 + 524288);   // block partials

    const int n = in_sizes[1] / 15;  // N rows (y_true is N x 15)
    const int gblocks = (n / 2 + 255) / 256;
    const int blocks = (n + 63) / 64;  // 64 rows per 1-wave block

    gate_kernel<<<gblocks, 256, 0, stream>>>(x, trip, valid, ptbl, combo, n);
    loss_kernel<<<blocks, 64, 0, stream>>>(combo, y_true, y_pred, mask, ptbl, partial, n);
    reduce_kernel<<<1, 256, 0, stream>>>(partial, out, blocks, 1.0f / (float)n);
}

// Round 12
// 183.220 us; speedup vs baseline: 1.0335x; 1.0335x over previous
//
#include <hip/hip_runtime.h>
#include <math.h>

#define NATOMS 5
#define NEXP 18
#define NBEAD 4
#define EPSV 1e-8f
#define ML2 (0.02f * 0.02f)

typedef float vf4a __attribute__((ext_vector_type(4), aligned(16)));
typedef float vf2u __attribute__((ext_vector_type(2), aligned(4)));

#define AS1U(p) ((const __attribute__((address_space(1))) unsigned*)(p))
#define AS3U(p) ((__attribute__((address_space(3))) unsigned*)(p))
#define CPOL_NT 2  // gfx940+ CPol: sc0=bit0, nt=bit1, sc1=bit4

// Pack per (expert,bead): 8 triplets, one 16-bit entry each in an int4.
// entry: oi | oj<<4 | ok<<8 | okflag<<12, offsets premultiplied by 3.
__global__ void pack_tables(const int* __restrict__ trip, const int* __restrict__ valid,
                            int4* __restrict__ ptbl) {
    int c = blockIdx.x * blockDim.x + threadIdx.x;
    if (c < NEXP * NBEAD) {
        unsigned w[4] = {0u, 0u, 0u, 0u};
#pragma unroll
        for (int t = 0; t < 8; t++) {
            int b = c * 8 + t;
            int i = trip[b * 3 + 0], j = trip[b * 3 + 1], k = trip[b * 3 + 2];
            unsigned ok = (i >= 0 && j >= 0 && k >= 0 && valid[b] > 0) ? 1u : 0u;
            unsigned oi = 3u * (unsigned)min(max(i, 0), NATOMS - 1);
            unsigned oj = 3u * (unsigned)min(max(j, 0), NATOMS - 1);
            unsigned ov = 3u * (unsigned)min(max(k, 0), NATOMS - 1);
            unsigned e = oi | (oj << 4) | (ov << 8) | (ok << 12);
            w[t >> 1] |= e << ((t & 1) * 16);
        }
        ptbl[c] = make_int4((int)w[0], (int)w[1], (int)w[2], (int)w[3]);
    }
}

// One wave per block, 64 rows per wave. Staging via global_load_lds DMA with
// NT cache policy (aux=2): no VGPR round trip, no ds_write chain, L1 bypass.
// Each array = 4 chunks x (64 lanes x 16B) = 4096B into a padded 1024-float
// LDS array (interior tiles over-stage 64 floats into the pad — safe).
// LDS: 3 * 4096 = 12288 B -> 13 wave-blocks/CU.
__global__ __launch_bounds__(64) void loss_kernel(
    const float* __restrict__ xin, const float* __restrict__ y_true,
    const float* __restrict__ y_pred, const float* __restrict__ mask,
    const int4* __restrict__ ptbl, float* __restrict__ partial, int n) {
    __shared__ float sT[1024];  // 64 rows x 15 (+64 pad)
    __shared__ float sP[1024];
    __shared__ float sM[1024];

    const int tid = threadIdx.x;  // 0..63
    const int rbase = blockIdx.x * 64;
    const int row = rbase + tid;
    const size_t dbase = (size_t)rbase * 15;  // dword offset, 3840B-aligned
    const long long total = (long long)n * 15;

    // ---- gate pair first (scattered 1-line-per-lane gather, NT) ----
    vf2u gb;
    gb.x = 0.f; gb.y = 0.f;
    if (row < n) gb = __builtin_nontemporal_load((const vf2u*)(xin + (size_t)row * 38 + 36));

    const vf4a* qT = (const vf4a*)(y_true + dbase);
    const vf4a* qP = (const vf4a*)(y_pred + dbase);
    const vf4a* qM = (const vf4a*)(mask + dbase);

    if (dbase + 1024 <= total) {
        // ---- fast path: direct-to-LDS DMA, NT policy, fire-and-forget ----
#pragma unroll
        for (int k = 0; k < 4; k++) {
            __builtin_amdgcn_global_load_lds(AS1U(qT + k * 64 + tid),
                                             AS3U((vf4a*)sT + k * 64), 16, 0, CPOL_NT);
            __builtin_amdgcn_global_load_lds(AS1U(qP + k * 64 + tid),
                                             AS3U((vf4a*)sP + k * 64), 16, 0, CPOL_NT);
            __builtin_amdgcn_global_load_lds(AS1U(qM + k * 64 + tid),
                                             AS3U((vf4a*)sM + k * 64), 16, 0, CPOL_NT);
        }
    } else {
        // ---- tail tile: guarded VGPR path (exact 240 chunks) ----
        vf4a tC[4], pC[4], mC[4];
        bool ok[4];
#pragma unroll
        for (int k = 0; k < 4; k++) {
            int q = k * 64 + tid;
            ok[k] = (q < 240) && (dbase + 4 * (long long)q + 4 <= total);
            if (ok[k]) {
                tC[k] = __builtin_nontemporal_load(qT + q);
                pC[k] = __builtin_nontemporal_load(qP + q);
                mC[k] = __builtin_nontemporal_load(qM + q);
            }
        }
#pragma unroll
        for (int k = 0; k < 4; k++) {
            int q = k * 64 + tid;
            if (ok[k]) {
                ((vf4a*)sT)[q] = tC[k];
                ((vf4a*)sP)[q] = pC[k];
                ((vf4a*)sM)[q] = mC[k];
            }
        }
    }
    __builtin_amdgcn_s_waitcnt(0);  // drain DMA (vmcnt) + LDS (lgkm)
    __syncthreads();                // 1-wave block: ordering only

    float result = 0.f;
    if (row < n) {
        const float* st = sT + tid * 15;  // stride 15 -> 2-way bank alias = free
        const float* sp = sP + tid * 15;
        const float* sm = sM + tid * 15;

        // ---- mask bits (binary mask -> exact) ----
        unsigned mrow = 0u;
#pragma unroll
        for (int c = 0; c < 15; c++) mrow |= (sm[c] > 0.f ? 1u : 0u) << c;

        // ---- atom MSE ----
        float num_a = 0.f, den_a = 0.f;
        unsigned avm2 = 0u;  // validity bit at premultiplied offset 3*a
#pragma unroll
        for (int a = 0; a < 5; a++) {
            unsigned mb = (mrow >> (3 * a)) & 7u;
            float d0 = st[3 * a + 0] - sp[3 * a + 0];
            float d1 = st[3 * a + 1] - sp[3 * a + 1];
            float d2 = st[3 * a + 2] - sp[3 * a + 2];
            float se = (mb & 1u ? d0 * d0 : 0.f) + (mb & 2u ? d1 * d1 : 0.f) +
                       (mb & 4u ? d2 * d2 : 0.f);
            if (mb) { num_a += se; den_a += 1.f; avm2 |= 1u << (3 * a); }
        }
        result = num_a / (den_a + EPSV);

        // ---- gate decode + table fetch (tiny, cached) ----
        float beadf = isfinite(gb.x) ? gb.x : 0.f;
        float gatef = isfinite(gb.y) ? gb.y : 0.f;
        gatef = fminf(fmaxf(gatef, -1e6f), 1e6f);
        beadf = fminf(fmaxf(beadf, -1e6f), 1e6f);
        int rid = min(max((int)rintf(gatef) - 1, 0), NEXP - 1);
        int bid = min(max((int)rintf(beadf), 0), NBEAD - 1);
        int4 pk = ptbl[rid * NBEAD + bid];
        unsigned tw0 = (unsigned)pk.x, tw1 = (unsigned)pk.y;
        unsigned tw2 = (unsigned)pk.z, tw3 = (unsigned)pk.w;

        // ---- angle part: dynamic gathers from own LDS row ----
        float num_g = 0.f, den_g = 0.f;
#pragma unroll
        for (int t = 0; t < 8; t++) {
            unsigned wrd = (t < 2) ? tw0 : (t < 4) ? tw1 : (t < 6) ? tw2 : tw3;
            unsigned e = (wrd >> ((t & 1) * 16)) & 0xffffu;
            int oi = e & 15, oj = (e >> 4) & 15, ov = (e >> 8) & 15;
            bool wok = ((e >> 12) & 1u) != 0u;

            float tix = st[oi], tiy = st[oi + 1], tiz = st[oi + 2];
            float tjx = st[oj], tjy = st[oj + 1], tjz = st[oj + 2];
            float tkx = st[ov], tky = st[ov + 1], tkz = st[ov + 2];
            float pix = sp[oi], piy = sp[oi + 1], piz = sp[oi + 2];
            float pjx = sp[oj], pjy = sp[oj + 1], pjz = sp[oj + 2];
            float pkx = sp[ov], pky = sp[ov + 1], pkz = sp[ov + 2];

            float v1tx = tix - tjx, v1ty = tiy - tjy, v1tz = tiz - tjz;
            float v2tx = tkx - tjx, v2ty = tky - tjy, v2tz = tkz - tjz;
            float v1px = pix - pjx, v1py = piy - pjy, v1pz = piz - pjz;
            float v2px = pkx - pjx, v2py = pky - pjy, v2pz = pkz - pjz;

            float l1t = fmaf(v1tx, v1tx, fmaf(v1ty, v1ty, v1tz * v1tz));
            float l2t = fmaf(v2tx, v2tx, fmaf(v2ty, v2ty, v2tz * v2tz));
            float l1p = fmaf(v1px, v1px, fmaf(v1py, v1py, v1pz * v1pz));
            float l2p = fmaf(v2px, v2px, fmaf(v2py, v2py, v2pz * v2pz));

            bool okv = wok && ((avm2 >> oi) & 1) && ((avm2 >> oj) & 1) &&
                       ((avm2 >> ov) & 1) && (l1t > ML2) && (l2t > ML2) &&
                       (l1p > ML2) && (l2p > ML2);

            float rt = __builtin_amdgcn_rsqf(fmaxf(l1t, ML2) * fmaxf(l2t, ML2));
            float rp = __builtin_amdgcn_rsqf(fmaxf(l1p, ML2) * fmaxf(l2p, ML2));

            float dott = fmaf(v1tx, v2tx, fmaf(v1ty, v2ty, v1tz * v2tz));
            float dotp = fmaf(v1px, v2px, fmaf(v1py, v2py, v1pz * v2pz));
            float cut = dott * rt;
            float cup = dotp * rp;
            float cost = fminf(fmaxf(cut, -1.f + 1e-6f), 1.f - 1e-6f);
            float cosp = fminf(fmaxf(cup, -1.f + 1e-6f), 1.f - 1e-6f);
            float sint = __builtin_amdgcn_sqrtf(fmaxf(fmaf(-cut, cut, 1.f), 0.f));
            float sinp = __builtin_amdgcn_sqrtf(fmaxf(fmaf(-cup, cup, 1.f), 0.f));

            float dc = cosp - cost, dsn = sinp - sint;
            if (okv) { num_g += fmaf(dc, dc, dsn * dsn); den_g += 1.f; }
        }
        result += num_g / (den_g + EPSV);
    }

    // ---- wave reduction: block == wave ----
#pragma unroll
    for (int off = 32; off > 0; off >>= 1)
        result += __shfl_down(result, off, 64);
    if (tid == 0) partial[blockIdx.x] = result;
}

__global__ __launch_bounds__(256) void reduce_kernel(const float* __restrict__ partial,
                                                     float* __restrict__ out, int m,
                                                     float inv_n) {
    __shared__ float red[4];
    float s = 0.f;
    for (int i = threadIdx.x; i < m; i += 256) s += partial[i];
#pragma unroll
    for (int off = 32; off > 0; off >>= 1) s += __shfl_down(s, off, 64);
    int lane = threadIdx.x & 63, wv = threadIdx.x >> 6;
    if (lane == 0) red[wv] = s;
    __syncthreads();
    if (threadIdx.x == 0) out[0] = (red[0] + red[1] + red[2] + red[3]) * inv_n;
}

extern "C" void kernel_launch(void* const* d_in, const int* in_sizes, int n_in,
                              void* d_out, int out_size, void* d_ws, size_t ws_size,
                              hipStream_t stream) {
    const float* x = (const float*)d_in[0];
    const float* y_true = (const float*)d_in[1];
    const float* y_pred = (const float*)d_in[2];
    const float* mask = (const float*)d_in[3];
    const int* trip = (const int*)d_in[4];
    const int* valid = (const int*)d_in[5];
    float* out = (float*)d_out;

    int4* ptbl = (int4*)d_ws;                       // 72 * 16 B
    float* partial = (float*)((char*)d_ws + 4096);  // block partials (~31.3 KB)

    const int n = in_sizes[1] / 15;    // N rows (y_true is N x 15)
    const int blocks = (n + 63) / 64;  // 64 rows per 1-wave block

    pack_tables<<<1, 128, 0, stream>>>(trip, valid, ptbl);
    loss_kernel<<<blocks, 64, 0, stream>>>(x, y_true, y_pred, mask, ptbl, partial, n);
    reduce_kernel<<<1, 256, 0, stream>>>(partial, out, blocks, 1.0f / (float)n);
}